// Round 8
// baseline (59.368 us; speedup 1.0000x reference)
//
#include <hip/hip_runtime.h>

#define D_IN  128
#define D_MID 256
#define D_OUT 16
#define NB    512
#define NN    8192
#define NROWS (NB + NN)   // 8704
#define BT    8           // query rows per KDE block
#define NSLICE 8          // n-slices for KDE
#define SLICE_N (NN / NSLICE)   // 1024

// ws floats: hidden[8704*256] | Ews[8704*16] | partial[2*8*512*16] | W1T[32768] | W2T[1024]
#define HID_OFF   0
#define EW_OFF    (NROWS * D_MID)                        // 2228224
#define PART_OFF  (EW_OFF + NROWS * D_OUT)               // 2367488
#define W1T_OFF   (PART_OFF + 2 * NSLICE * NB * D_OUT)   // 2498560
#define W2T_OFF   (W1T_OFF + D_MID * D_IN)               // 2531328

// ---------------- Kernel 0: transpose W1, W2 to coalesced layouts ----------------
__global__ __launch_bounds__(256) void transpose_kernel(
    const float* __restrict__ W1, const float* __restrict__ W2,
    float* __restrict__ W1T, float* __restrict__ W2T)
{
    const int tid = blockIdx.x * 256 + threadIdx.x;
    if (tid < 8192) {
        const int k4 = tid >> 8;            // 0..31
        const int j  = tid & 255;           // 0..255
        const float4 v = reinterpret_cast<const float4*>(W1)[(size_t)j * 32 + k4];
        // W1T[k][j] scalar layout: write 4 k-rows
        W1T[(size_t)(k4 * 4 + 0) * D_MID + j] = v.x;
        W1T[(size_t)(k4 * 4 + 1) * D_MID + j] = v.y;
        W1T[(size_t)(k4 * 4 + 2) * D_MID + j] = v.z;
        W1T[(size_t)(k4 * 4 + 3) * D_MID + j] = v.w;
    } else {
        const int t2 = tid - 8192;          // 0..1023
        const int j4 = t2 >> 4;             // 0..63
        const int d  = t2 & 15;             // 0..15
        const float4 v = reinterpret_cast<const float4*>(W2)[(size_t)d * 64 + j4];
        reinterpret_cast<float4*>(W2T)[(size_t)j4 * 16 + d] = v;
    }
}

// ---------------- Kernel 1: fc1 — hidden = relu(rows @ W1^T) ----------------
// 544 blocks (272 row-blocks x 2 col-halves), 256 threads.
// Block tile 32 rows x 128 cols; per-thread 4x4 outer-product tile.
// Rows in LDS once; W1 panels (32k x 128c) double-buffered via reg-staging.
// Inner loop is pure LDS+VALU: 1 ds_read_b128 + 4 broadcast b32 per 16 fma.
__global__ __launch_bounds__(256) void fc1_kernel(
    const float* __restrict__ x, const float* __restrict__ calc_X,
    const float* __restrict__ W1T, float* __restrict__ hidden)
{
    __shared__ float rows[32][132];        // 16.9 KB, b128-aligned rows
    __shared__ float w1lds[2][32][128];    // 32 KB, linear

    const int t    = threadIdx.x;
    const int rb   = blockIdx.x >> 1;
    const int ch   = blockIdx.x & 1;
    const int row0 = rb * 32;
    const int wave = t >> 6;
    const int lane = t & 63;
    const int tg_r = t >> 5;     // 0..7
    const int tg_c = t & 31;     // 0..31

    // NB=512 = 16 row-blocks -> each block purely x or purely calc_X
    const float* __restrict__ rbase = (row0 < NB)
        ? (x + (size_t)row0 * D_IN)
        : (calc_X + (size_t)(row0 - NB) * D_IN);

    // ---- stage 32 rows (1024 float4, coalesced, conflict-free-enough writes) ----
    {
        const float4* __restrict__ row4 = reinterpret_cast<const float4*>(rbase);
#pragma unroll
        for (int q = 0; q < 4; ++q) {
            const int idx = t + q * 256;    // 0..1023: r = idx>>5, k4 = idx&31
            const float4 v = row4[idx];
            *reinterpret_cast<float4*>(&rows[idx >> 5][(idx & 31) * 4]) = v;
        }
    }

    // W1T col-slice for this block: f4 element [k*64 + c4] = W1T[k][ch*128 + c4*4..]
    const float4* __restrict__ w1g = reinterpret_cast<const float4*>(W1T + ch * 128);

    float4 wreg[4];
#define LOAD_PANEL(p)                                                   \
    {                                                                   \
        _Pragma("unroll")                                               \
        for (int q = 0; q < 4; ++q) {                                   \
            const int idx = (wave * 4 + q) * 64 + lane;                 \
            const int kk  = idx >> 5;                                   \
            const int c4  = idx & 31;                                   \
            wreg[q] = w1g[(size_t)((p) * 32 + kk) * 64 + c4];           \
        }                                                               \
    }
#define WRITE_PANEL(buf)                                                \
    {                                                                   \
        _Pragma("unroll")                                               \
        for (int q = 0; q < 4; ++q) {                                   \
            const int idx = (wave * 4 + q) * 64 + lane;                 \
            const int kk  = idx >> 5;                                   \
            const int c4  = idx & 31;                                   \
            *reinterpret_cast<float4*>(&w1lds[buf][kk][c4 * 4]) = wreg[q]; \
        }                                                               \
    }

    LOAD_PANEL(0);
    WRITE_PANEL(0);
    __syncthreads();

    float acc[4][4] = {};
    const int r0 = tg_r * 4;
    const int c0 = tg_c * 4;

    for (int p = 0; p < 4; ++p) {
        const int buf = p & 1;
        if (p < 3) LOAD_PANEL(p + 1);       // issue early; hides under compute
#pragma unroll 8
        for (int kk = 0; kk < 32; ++kk) {
            const float4 wv = *reinterpret_cast<const float4*>(&w1lds[buf][kk][c0]);
            const int k = p * 32 + kk;
            const float r0v = rows[r0 + 0][k];
            const float r1v = rows[r0 + 1][k];
            const float r2v = rows[r0 + 2][k];
            const float r3v = rows[r0 + 3][k];
            acc[0][0] = fmaf(r0v, wv.x, acc[0][0]);
            acc[0][1] = fmaf(r0v, wv.y, acc[0][1]);
            acc[0][2] = fmaf(r0v, wv.z, acc[0][2]);
            acc[0][3] = fmaf(r0v, wv.w, acc[0][3]);
            acc[1][0] = fmaf(r1v, wv.x, acc[1][0]);
            acc[1][1] = fmaf(r1v, wv.y, acc[1][1]);
            acc[1][2] = fmaf(r1v, wv.z, acc[1][2]);
            acc[1][3] = fmaf(r1v, wv.w, acc[1][3]);
            acc[2][0] = fmaf(r2v, wv.x, acc[2][0]);
            acc[2][1] = fmaf(r2v, wv.y, acc[2][1]);
            acc[2][2] = fmaf(r2v, wv.z, acc[2][2]);
            acc[2][3] = fmaf(r2v, wv.w, acc[2][3]);
            acc[3][0] = fmaf(r3v, wv.x, acc[3][0]);
            acc[3][1] = fmaf(r3v, wv.y, acc[3][1]);
            acc[3][2] = fmaf(r3v, wv.z, acc[3][2]);
            acc[3][3] = fmaf(r3v, wv.w, acc[3][3]);
        }
        __syncthreads();                    // all reads of buf done
        if (p < 3) {
            WRITE_PANEL(buf ^ 1);
            __syncthreads();                // panel visible before next reads
        }
    }

    // ---- relu + store (f4-coalesced) ----
#pragma unroll
    for (int i = 0; i < 4; ++i) {
        float4 o;
        o.x = fmaxf(acc[i][0], 0.f);
        o.y = fmaxf(acc[i][1], 0.f);
        o.z = fmaxf(acc[i][2], 0.f);
        o.w = fmaxf(acc[i][3], 0.f);
        *reinterpret_cast<float4*>(
            hidden + (size_t)(row0 + r0 + i) * D_MID + ch * 128 + c0) = o;
    }
#undef LOAD_PANEL
#undef WRITE_PANEL
}

// ---------------- Kernel 2: fc2 — Ews = s * (hidden @ W2^T) ----------------
// 1088 blocks, 8 rows/block, 256 threads = 8r x 2half x 16d, shfl combine.
__global__ __launch_bounds__(256) void fc2_kernel(
    const float* __restrict__ hidden, const float* __restrict__ W2T,
    const float* __restrict__ hptr, float* __restrict__ Ews)
{
    const int t    = threadIdx.x;
    const int rloc = t >> 5;            // 0..7
    const int half = (t >> 4) & 1;
    const int d    = t & 15;
    const int r    = blockIdx.x * 8 + rloc;

    const float4* __restrict__ h4 =
        reinterpret_cast<const float4*>(hidden + (size_t)r * D_MID) + half * 32;
    const float4* __restrict__ w4 =
        reinterpret_cast<const float4*>(W2T) + half * 32 * 16;

    float4 a = make_float4(0.f, 0.f, 0.f, 0.f);
#pragma unroll 8
    for (int j4 = 0; j4 < 32; ++j4) {
        const float4 hv = h4[j4];
        const float4 wv = w4[j4 * 16 + d];
        a.x = fmaf(hv.x, wv.x, a.x);
        a.y = fmaf(hv.y, wv.y, a.y);
        a.z = fmaf(hv.z, wv.z, a.z);
        a.w = fmaf(hv.w, wv.w, a.w);
    }
    float v = (a.x + a.y) + (a.z + a.w);
    v += __shfl_xor(v, 16, 64);
    if (half == 0) {
        const float s = 0.84932180028801904272f / hptr[0];   // sqrt(log2(e)/2)/h
        Ews[(size_t)r * D_OUT + d] = v * s;
    }
}

// ---------------- Kernel 3: partial KDE sums, w = exp2(-(xs-zs)^2) ----------------
// grid (NB/BT=64, NSLICE=8), 256 threads = 16 d x 16 chunk.
__global__ __launch_bounds__(256) void kde_kernel(
    const float* __restrict__ Ews, const float* __restrict__ Y,
    float* __restrict__ partial)
{
    __shared__ float red[4][16][16];   // [wave][d][bt*2 + {num,den}]

    const int t     = threadIdx.x;
    const int d     = t & 15;
    const int chunk = t >> 4;          // 0..15
    const int b0    = blockIdx.x * BT;
    const int slice = blockIdx.y;
    const float* __restrict__ Xws = Ews + (size_t)NB * D_OUT;

    float z[BT], num[BT] = {}, den[BT] = {};
#pragma unroll
    for (int bt = 0; bt < BT; ++bt)
        z[bt] = Ews[(size_t)(b0 + bt) * D_OUT + d];

#pragma unroll 4
    for (int i = 0; i < SLICE_N / 16; ++i) {        // 64 iterations
        const int n = slice * SLICE_N + i * 16 + chunk;
        const float xw = Xws[(size_t)n * D_OUT + d];   // 4B/lane, coalesced
        const float yv = Y[(size_t)n * D_OUT + d];
#pragma unroll
        for (int bt = 0; bt < BT; ++bt) {
            const float df = xw - z[bt];
            const float w  = __builtin_amdgcn_exp2f(-(df * df));
            den[bt] += w;
            num[bt] = fmaf(w, yv, num[bt]);
        }
    }

    // ---- reduce over chunk lanes within wave: xor 16, 32 (2 levels) ----
    float vals[16];
#pragma unroll
    for (int bt = 0; bt < BT; ++bt) {
        vals[bt * 2 + 0] = num[bt];
        vals[bt * 2 + 1] = den[bt];
    }
#pragma unroll
    for (int m = 16; m <= 32; m <<= 1) {
#pragma unroll
        for (int v = 0; v < 16; ++v)
            vals[v] += __shfl_xor(vals[v], m, 64);
    }

    const int wave = t >> 6;
    if ((t & 63) < 16) {
#pragma unroll
        for (int v = 0; v < 16; ++v) red[wave][d][v] = vals[v];
    }
    __syncthreads();

    // ---- 256 outputs: t = bt(8) x d(16) x p(2) ----
    {
        const int p  = t & 1;
        const int dd = (t >> 1) & 15;
        const int bt = t >> 5;
        const int v  = bt * 2 + p;
        const float sum = red[0][dd][v] + red[1][dd][v] + red[2][dd][v] + red[3][dd][v];
        partial[(size_t)(p * NSLICE + slice) * NB * D_OUT + (size_t)(b0 + bt) * D_OUT + dd] = sum;
    }
}

// ---------------- Kernel 4: combine slices + divide ----------------
__global__ __launch_bounds__(256) void combine_kernel(
    const float* __restrict__ partial, float* __restrict__ out)
{
    const int i = blockIdx.x * 256 + threadIdx.x;   // 0..8191
    float nsum = 0.f, dsum = 0.f;
#pragma unroll
    for (int s = 0; s < NSLICE; ++s) {
        nsum += partial[(size_t)s * NB * D_OUT + i];
        dsum += partial[(size_t)(NSLICE + s) * NB * D_OUT + i];
    }
    out[i] = nsum / dsum;
}

extern "C" void kernel_launch(void* const* d_in, const int* in_sizes, int n_in,
                              void* d_out, int out_size, void* d_ws, size_t ws_size,
                              hipStream_t stream) {
    const float* x      = (const float*)d_in[0];
    const float* calc_X = (const float*)d_in[1];
    const float* calc_Y = (const float*)d_in[2];
    const float* W1     = (const float*)d_in[3];
    const float* W2     = (const float*)d_in[4];
    const float* h      = (const float*)d_in[5];

    float* ws      = (float*)d_ws;
    float* hidden  = ws + HID_OFF;
    float* Ews     = ws + EW_OFF;
    float* partial = ws + PART_OFF;
    float* W1T     = ws + W1T_OFF;
    float* W2T     = ws + W2T_OFF;
    float* out     = (float*)d_out;

    transpose_kernel<<<dim3(36), dim3(256), 0, stream>>>(W1, W2, W1T, W2T);
    fc1_kernel<<<dim3(544), dim3(256), 0, stream>>>(x, calc_X, W1T, hidden);
    fc2_kernel<<<dim3(NROWS / 8), dim3(256), 0, stream>>>(hidden, W2T, h, Ews);
    kde_kernel<<<dim3(NB / BT, NSLICE), dim3(256), 0, stream>>>(Ews, calc_Y, partial);
    combine_kernel<<<dim3(NB * D_OUT / 256), dim3(256), 0, stream>>>(partial, out);
}